// Round 2
// baseline (128.272 us; speedup 1.0000x reference)
//
#include <hip/hip_runtime.h>

#define NQ 4096           // B
#define TT 819200         // T
#define MUF 3.5f

__global__ __launch_bounds__(256) void asvd_kernel(
    const float* __restrict__ bu, const float* __restrict__ bi,
    const float* __restrict__ Q,  const float* __restrict__ X,
    const float* __restrict__ Y,
    const int* __restrict__ user, const int* __restrict__ item,
    const int* __restrict__ imp_items, const int* __restrict__ imp_ratings,
    const int* __restrict__ seg, float* __restrict__ out)
{
    const int b   = blockIdx.x;
    const int tid = threadIdx.x;

    // lower_bound over sorted segment_ids (all threads redundantly, uniform)
    auto lower = [&](int key) {
        int lo = 0, hi = TT;
        while (lo < hi) {
            int mid = (lo + hi) >> 1;
            if (seg[mid] < key) lo = mid + 1; else hi = mid;
        }
        return lo;
    };
    const int start = lower(b);
    const int end   = lower(b + 1);
    const int count = end - start;

    const int   u    = user[b];
    const int   it   = item[b];
    const float bu_u = bu[u];
    const float bui  = MUF + bu_u + bi[it];

    const int g = tid >> 5;   // entry group 0..7
    const int l = tid & 31;   // lane within group: float4 slot of the 128-dim row

    const float4* __restrict__ X4 = (const float4*)X;
    const float4* __restrict__ Y4 = (const float4*)Y;
    const float4* __restrict__ Q4 = (const float4*)Q;

    const int STEP = 8;
    float4 a0 = make_float4(0.f,0.f,0.f,0.f);
    float4 a1 = make_float4(0.f,0.f,0.f,0.f);
    float4 a2 = make_float4(0.f,0.f,0.f,0.f);
    float4 a3 = make_float4(0.f,0.f,0.f,0.f);

    int t = start + g;
    // 4x-unrolled main loop: 4 independent dependence chains per group
    for (; t + 3*STEP < end; t += 4*STEP) {
        const int j0 = imp_items[t];
        const int j1 = imp_items[t +   STEP];
        const int j2 = imp_items[t + 2*STEP];
        const int j3 = imp_items[t + 3*STEP];
        const int r0 = imp_ratings[t];
        const int r1 = imp_ratings[t +   STEP];
        const int r2 = imp_ratings[t + 2*STEP];
        const int r3 = imp_ratings[t + 3*STEP];

        const float w0 = (float)r0 - MUF - bu_u - bi[j0];
        const float w1 = (float)r1 - MUF - bu_u - bi[j1];
        const float w2 = (float)r2 - MUF - bu_u - bi[j2];
        const float w3 = (float)r3 - MUF - bu_u - bi[j3];

        const float4 x0 = X4[(size_t)j0 * 32 + l];
        const float4 x1 = X4[(size_t)j1 * 32 + l];
        const float4 x2 = X4[(size_t)j2 * 32 + l];
        const float4 x3 = X4[(size_t)j3 * 32 + l];
        const float4 y0 = Y4[(size_t)j0 * 32 + l];
        const float4 y1 = Y4[(size_t)j1 * 32 + l];
        const float4 y2 = Y4[(size_t)j2 * 32 + l];
        const float4 y3 = Y4[(size_t)j3 * 32 + l];

        a0.x += w0 * x0.x + y0.x;  a0.y += w0 * x0.y + y0.y;
        a0.z += w0 * x0.z + y0.z;  a0.w += w0 * x0.w + y0.w;
        a1.x += w1 * x1.x + y1.x;  a1.y += w1 * x1.y + y1.y;
        a1.z += w1 * x1.z + y1.z;  a1.w += w1 * x1.w + y1.w;
        a2.x += w2 * x2.x + y2.x;  a2.y += w2 * x2.y + y2.y;
        a2.z += w2 * x2.z + y2.z;  a2.w += w2 * x2.w + y2.w;
        a3.x += w3 * x3.x + y3.x;  a3.y += w3 * x3.y + y3.y;
        a3.z += w3 * x3.z + y3.z;  a3.w += w3 * x3.w + y3.w;
    }
    // tail
    for (; t < end; t += STEP) {
        const int   j = imp_items[t];
        const float w = (float)imp_ratings[t] - MUF - bu_u - bi[j];
        const float4 x = X4[(size_t)j * 32 + l];
        const float4 y = Y4[(size_t)j * 32 + l];
        a0.x += w * x.x + y.x;  a0.y += w * x.y + y.y;
        a0.z += w * x.z + y.z;  a0.w += w * x.w + y.w;
    }

    a0.x += a1.x + a2.x + a3.x;  a0.y += a1.y + a2.y + a3.y;
    a0.z += a1.z + a2.z + a3.z;  a0.w += a1.w + a2.w + a3.w;

    const float4 q = Q4[(size_t)it * 32 + l];
    float partial = a0.x * q.x + a0.y * q.y + a0.z * q.z + a0.w * q.w;

    // reduce 256 threads: wave64 shuffle tree, then LDS across 4 waves
    #pragma unroll
    for (int off = 32; off > 0; off >>= 1)
        partial += __shfl_down(partial, off, 64);

    __shared__ float red[4];
    if ((tid & 63) == 0) red[tid >> 6] = partial;
    __syncthreads();
    if (tid == 0) {
        const float total = red[0] + red[1] + red[2] + red[3];
        const float norm  = (count > 0) ? rsqrtf((float)count) : 1.0f;
        out[b] = bui + norm * total;
    }
}

extern "C" void kernel_launch(void* const* d_in, const int* in_sizes, int n_in,
                              void* d_out, int out_size, void* d_ws, size_t ws_size,
                              hipStream_t stream) {
    const float* bu = (const float*)d_in[0];
    const float* bi = (const float*)d_in[1];
    const float* Q  = (const float*)d_in[2];
    const float* X  = (const float*)d_in[3];
    const float* Y  = (const float*)d_in[4];
    const int* user        = (const int*)d_in[5];
    const int* item        = (const int*)d_in[6];
    const int* imp_items   = (const int*)d_in[7];
    const int* imp_ratings = (const int*)d_in[8];
    const int* seg         = (const int*)d_in[9];
    float* out = (float*)d_out;

    asvd_kernel<<<NQ, 256, 0, stream>>>(bu, bi, Q, X, Y, user, item,
                                        imp_items, imp_ratings, seg, out);
}